// Round 14
// baseline (18.212 us; speedup 1.0000x reference)
//
#include <hip/hip_runtime.h>
#include <hip/hip_bf16.h>
#include <math.h>

// Steerable CNP target prediction — separable RBF + bf16 MFMA.
//
// out[t,c] = (sum_i Kx[t,i] * V[t,c,i]) / (Sx[t]*Sy[t]),
//   V[t,c,i] = sum_j Ky[t,j] * FMc[j,i]   <- GEMM: mfma_f32_16x16x32_bf16
//
// Round 14 = r11 (best, 15.1us) + Sx/Sy moved to the prep kernel (64 KB
// table, 32 extra blocks running parallel to the 64 pack blocks). Main
// kernel: phase0 writes only Kx + kyA (no Ky32), no in-kernel S-reduce --
// the 500cy dependent-shuffle chain between barrier and MFMA is gone.
// Lessons kept: named regs (r1), no forced occupancy (r3), VGPR<128 (r4),
// packed coalesced B (r10), prefetch-before-use (r11), no big tables (r12),
// exps in bulk not per-lane-scalar (r13).

#define NA      128
#define TT      16
#define THREADS 512

typedef __attribute__((ext_vector_type(8))) short short8;
typedef __attribute__((ext_vector_type(4))) float f32x4;

__device__ __forceinline__ short f2bf(float x) {
    __hip_bfloat16 h = __float2bfloat16(x);
    return *reinterpret_cast<short*>(&h);
}

// ---------------- prep kernel ----------------
// blocks [0,64):    bfB pack (identical to r11 pack_pre)
// blocks [64,64+ns): Sx/Sy tables, one thread per target
__global__ __launch_bounds__(256)
void prep(const float* __restrict__ fm, const float* __restrict__ grid,
          const float* __restrict__ xt, const float* __restrict__ lsp,
          short* __restrict__ bfB, float* __restrict__ SxT,
          float* __restrict__ SyT, int n_target)
{
    const int tid = threadIdx.x;

    if (blockIdx.x < 64) {                       // ---- bfB pack ----
        const int idx = blockIdx.x * 256 + tid;  // 16384 = 4c x 128k x 32 i4
        const int c  = idx >> 12;
        const int k  = (idx >> 5) & 127;
        const int i0 = (idx & 31) * 4;
        float4 v = *reinterpret_cast<const float4*>(fm + c * NA * NA + k * NA + i0);
        if (c >= 2) {
            v.x = (v.x > 15.0f) ? v.x : log1pf(__expf(v.x));
            v.y = (v.y > 15.0f) ? v.y : log1pf(__expf(v.y));
            v.z = (v.z > 15.0f) ? v.z : log1pf(__expf(v.z));
            v.w = (v.w > 15.0f) ? v.w : log1pf(__expf(v.w));
        }
        const int s  = k >> 5;
        const int e  = k & 7;
        const int Lk = ((k >> 3) & 3) * 16;
        const float vv[4] = {v.x, v.y, v.z, v.w};
#pragma unroll
        for (int d = 0; d < 4; ++d) {
            const int i = i0 + d;
            const int n = i >> 4;
            const int L = Lk + (i & 15);
            bfB[(((c * 8 + n) * 4 + s) * 64 + L) * 8 + e] = f2bf(vv[d]);
        }
        return;
    }

    // ---- S tables: one thread per target ----
    const int t = (blockIdx.x - 64) * 256 + tid;
    if (t >= n_target) return;
    const float x0 = xt[t * 2 + 0];
    const float x1 = xt[t * 2 + 1];
    const float l      = lsp[0];
    const float inv2l2 = 0.5f / (l * l);
    float sx = 0.f, sy = 0.f;
#pragma unroll 4
    for (int j = 0; j < NA; ++j) {
        const float ax = grid[j * 2 + 1];        // ax[j] = grid[j*2+1]
        const float dx = x0 - ax, dy = x1 - ax;
        sx += __expf(-dx * dx * inv2l2);
        sy += __expf(-dy * dy * inv2l2);
    }
    SxT[t] = sx;
    SyT[t] = sy;
}

// ---------------- main kernel ----------------
__global__ __launch_bounds__(THREADS)
void cnp_mfma(const short* __restrict__ bfB,   // [4][8][4][64][8] bf16
              const float* __restrict__ grid,  // [NA*NA][2]
              const float* __restrict__ xt,    // [T][2]
              const float* __restrict__ lsp,   // [1]
              const float* __restrict__ SxT, const float* __restrict__ SyT,
              float* __restrict__ out,         // means [T][2] then sigmas [T][2]
              int n_target)
{
    __shared__ __attribute__((aligned(16))) float Kx[TT * NA];      // 8 KB
    __shared__ __attribute__((aligned(16))) short kyA[4 * 64 * 8];  // 4 KB, A-frags
    __shared__ float red[4][2][TT];

    const int tid  = threadIdx.x;
    const int wid  = tid >> 6;
    const int c    = wid & 3;         // channel
    const int nh   = wid >> 2;        // n-half
    const int lane = tid & 63;
    const int t0   = blockIdx.x * TT;

    // ---- B-frag prefetch (latency hides under phase 0) ----
    const short8* bbase = reinterpret_cast<const short8*>(bfB)
                        + c * 2048 + nh * 1024 + lane;
    const short8 b00 = bbase[0],         b01 = bbase[64],
                 b02 = bbase[128],       b03 = bbase[192];
    const short8 b10 = bbase[256],       b11 = bbase[256 + 64],
                 b12 = bbase[256 + 128], b13 = bbase[256 + 192];
    const short8 b20 = bbase[512],       b21 = bbase[512 + 64],
                 b22 = bbase[512 + 128], b23 = bbase[512 + 192];
    const short8 b30 = bbase[768],       b31 = bbase[768 + 64],
                 b32 = bbase[768 + 128], b33 = bbase[768 + 192];

    const float l      = lsp[0];
    const float inv2l2 = 0.5f / (l * l);

    // ---- phase 0: exps -> LDS (Kx fp32 + kyA bf16 A-frags only) ----
    // grid[g] = (ax[g>>7], ax[g&127])  =>  ax[j] = grid[j*2+1]
#pragma unroll
    for (int s = 0; s < 4; ++s) {
        const int k = s * THREADS + tid;   // 0..2047
        const int t = k >> 7;
        const int j = k & 127;
        int tg = t0 + t; if (tg >= n_target) tg = n_target - 1;
        const float ax = grid[j * 2 + 1];
        const float dx = xt[tg * 2 + 0] - ax;
        const float dy = xt[tg * 2 + 1] - ax;
        Kx[t * NA + j] = __expf(-dx * dx * inv2l2);
        // Ky -> A-fragment layout: m = t (0..15), k-pos = j
        const int ss = j >> 5, g = (j & 31) >> 3, e = j & 7;
        kyA[((ss * 64) + g * 16 + (t & 15)) * 8 + e] = f2bf(__expf(-dy * dy * inv2l2));
    }
    __syncthreads();

    // ---- A-frags ----
    const short8* kap = reinterpret_cast<const short8*>(kyA);
    const short8 a0 = kap[0 * 64 + lane];
    const short8 a1 = kap[1 * 64 + lane];
    const short8 a2 = kap[2 * 64 + lane];
    const short8 a3 = kap[3 * 64 + lane];

    // ---- MFMA + stage-2 dot ----
    const int icol = lane & 15;
    const int tb   = (lane >> 4) * 4;
    f32x4 p = {0.f, 0.f, 0.f, 0.f};

#define NTILE(NN, B0, B1, B2, B3)                                              \
    {                                                                          \
        f32x4 acc = {0.f, 0.f, 0.f, 0.f};                                      \
        acc = __builtin_amdgcn_mfma_f32_16x16x32_bf16(a0, B0, acc, 0, 0, 0);   \
        acc = __builtin_amdgcn_mfma_f32_16x16x32_bf16(a1, B1, acc, 0, 0, 0);   \
        acc = __builtin_amdgcn_mfma_f32_16x16x32_bf16(a2, B2, acc, 0, 0, 0);   \
        acc = __builtin_amdgcn_mfma_f32_16x16x32_bf16(a3, B3, acc, 0, 0, 0);   \
        const int i = (nh * 4 + (NN)) * 16 + icol;                             \
        p.x = fmaf(Kx[(tb + 0) * NA + i], acc.x, p.x);                         \
        p.y = fmaf(Kx[(tb + 1) * NA + i], acc.y, p.y);                         \
        p.z = fmaf(Kx[(tb + 2) * NA + i], acc.z, p.z);                         \
        p.w = fmaf(Kx[(tb + 3) * NA + i], acc.w, p.w);                         \
    }
    NTILE(0, b00, b01, b02, b03)
    NTILE(1, b10, b11, b12, b13)
    NTILE(2, b20, b21, b22, b23)
    NTILE(3, b30, b31, b32, b33)
#undef NTILE

    // ---- reduce numer over the 16 i-lanes (strides 1,2,4,8) ----
#pragma unroll
    for (int st = 1; st <= 8; st <<= 1) {
        p.x += __shfl_xor(p.x, st);
        p.y += __shfl_xor(p.y, st);
        p.z += __shfl_xor(p.z, st);
        p.w += __shfl_xor(p.w, st);
    }
    if (icol == 0) {
        red[c][nh][tb + 0] = p.x;
        red[c][nh][tb + 1] = p.y;
        red[c][nh][tb + 2] = p.z;
        red[c][nh][tb + 3] = p.w;
    }
    __syncthreads();

    // ---- epilogue: combine n-halves, normalize, write (64 outputs) ----
    if (tid < 4 * TT) {
        const int t  = tid & (TT - 1);
        const int cc = tid >> 4;            // requires TT == 16
        const int tg = t0 + t;
        if (tg < n_target) {
            const float numer = red[cc][0][t] + red[cc][1][t];
            const float val = numer / (SxT[tg] * SyT[tg]);
            if (cc < 2) out[tg * 2 + cc] = val;                        // means
            else        out[n_target * 2 + tg * 2 + (cc - 2)] = val;   // sigmas
        }
    }
}

extern "C" void kernel_launch(void* const* d_in, const int* in_sizes, int n_in,
                              void* d_out, int out_size, void* d_ws, size_t ws_size,
                              hipStream_t stream) {
    const float* fm   = (const float*)d_in[0];
    const float* grid = (const float*)d_in[1];
    const float* xt   = (const float*)d_in[2];
    const float* lsp  = (const float*)d_in[3];
    float* out = (float*)d_out;

    const int n_target = in_sizes[2] / 2;                   // 8192
    const int ns   = (n_target + 255) / 256;                // 32 S-table blocks
    const int nb16 = (n_target + TT - 1) / TT;              // 512 main blocks

    // ---- ws partition ----
    char* w = (char*)d_ws;
    short* bfB = (short*)w;   w += (size_t)65536 * 2;       // 128 KB
    float* SxT = (float*)w;   w += (size_t)ns * 256 * 4;    // 32 KB
    float* SyT = (float*)w;

    hipLaunchKernelGGL(prep, dim3(64 + ns), dim3(256), 0, stream,
                       fm, grid, xt, lsp, bfB, SxT, SyT, n_target);
    hipLaunchKernelGGL(cnp_mfma, dim3(nb16), dim3(THREADS), 0, stream,
                       bfB, grid, xt, lsp, SxT, SyT, out, n_target);
}

// Round 15
// 15.054 us; speedup vs baseline: 1.2098x; 1.2098x over previous
//
#include <hip/hip_runtime.h>
#include <hip/hip_bf16.h>
#include <math.h>

// Steerable CNP target prediction — separable RBF + bf16 MFMA.
//
// out[t,c] = (sum_i Kx[t,i] * V[t,c,i]) / (Sx[t]*Sy[t]),
//   V[t,c,i] = sum_j Ky[t,j] * FMc[j,i]   <- GEMM: mfma_f32_16x16x32_bf16
//
// Round 15 = r11 (best, 15.1us) + 2 target-tiles per block: B-frags are
// target-independent, so each block reuses its 64 B-VGPRs for 32 targets.
// bfB L2 traffic halves (64->32MB), blocks 512->256 (= 1/CU, no 2nd
// dispatch round). Same 2-barriers-per-tile (hazard analysis: Kx/kyA are
// fully consumed before the tile's 2nd barrier; epilogue reads red/psx
// before the next tile's 1st barrier). prep widened to 128 blocks x 128.
// Lessons: named regs (r1), no forced occ (r3), VGPR<128 (r4), packed B
// (r10), prefetch early (r11), no tables (r12), no serial prep blocks (r14).

#define NA      128
#define TT      16
#define TILES   2
#define THREADS 512

typedef __attribute__((ext_vector_type(8))) short short8;
typedef __attribute__((ext_vector_type(4))) float f32x4;

__device__ __forceinline__ short f2bf(float x) {
    __hip_bfloat16 h = __float2bfloat16(x);
    return *reinterpret_cast<short*>(&h);
}

// ---------- pre-kernel: FM -> softplus'd bf16 fragment-linear layout ----------
// bfB[(((c*8+n)*4+s)*64+L)*8+e] = FMc[k][i], k=s*32+((L>>4)&3)*8+e, i=n*16+(L&15)
__global__ __launch_bounds__(128)
void pack_pre(const float* __restrict__ fm, short* __restrict__ bfB)
{
    const int idx = blockIdx.x * 128 + threadIdx.x;   // 16384 = 4c x 128k x 32 i4
    const int c  = idx >> 12;
    const int k  = (idx >> 5) & 127;
    const int i0 = (idx & 31) * 4;

    float4 v = *reinterpret_cast<const float4*>(fm + c * NA * NA + k * NA + i0);
    if (c >= 2) {
        v.x = (v.x > 15.0f) ? v.x : log1pf(__expf(v.x));
        v.y = (v.y > 15.0f) ? v.y : log1pf(__expf(v.y));
        v.z = (v.z > 15.0f) ? v.z : log1pf(__expf(v.z));
        v.w = (v.w > 15.0f) ? v.w : log1pf(__expf(v.w));
    }
    const int s  = k >> 5;
    const int e  = k & 7;
    const int Lk = ((k >> 3) & 3) * 16;
    const float vv[4] = {v.x, v.y, v.z, v.w};
#pragma unroll
    for (int d = 0; d < 4; ++d) {
        const int i = i0 + d;
        const int n = i >> 4;
        const int L = Lk + (i & 15);
        bfB[(((c * 8 + n) * 4 + s) * 64 + L) * 8 + e] = f2bf(vv[d]);
    }
}

// ---------- main kernel ----------
__global__ __launch_bounds__(THREADS)
void cnp_mfma(const short* __restrict__ bfB,   // [4][8][4][64][8] bf16
              const float* __restrict__ grid,  // [NA*NA][2]
              const float* __restrict__ xt,    // [T][2]
              const float* __restrict__ lsp,   // [1]
              float* __restrict__ out,         // means [T][2] then sigmas [T][2]
              int n_target)
{
    __shared__ __attribute__((aligned(16))) float Kx[TT * NA];      // 8 KB
    __shared__ __attribute__((aligned(16))) float Ky32[TT * NA];    // 8 KB
    __shared__ __attribute__((aligned(16))) short kyA[4 * 64 * 8];  // 4 KB
    __shared__ float psx[TT], psy[TT];
    __shared__ float red[4][2][TT];

    const int tid   = threadIdx.x;
    const int wid   = tid >> 6;
    const int c     = wid & 3;        // channel
    const int nh    = wid >> 2;       // n-half
    const int lane  = tid & 63;
    const int tbase = blockIdx.x * (TT * TILES);

    // ---- B-frag prefetch: once per block, reused by all tiles ----
    const short8* bbase = reinterpret_cast<const short8*>(bfB)
                        + c * 2048 + nh * 1024 + lane;
    const short8 b00 = bbase[0],         b01 = bbase[64],
                 b02 = bbase[128],       b03 = bbase[192];
    const short8 b10 = bbase[256],       b11 = bbase[256 + 64],
                 b12 = bbase[256 + 128], b13 = bbase[256 + 192];
    const short8 b20 = bbase[512],       b21 = bbase[512 + 64],
                 b22 = bbase[512 + 128], b23 = bbase[512 + 192];
    const short8 b30 = bbase[768],       b31 = bbase[768 + 64],
                 b32 = bbase[768 + 128], b33 = bbase[768 + 192];

    const float l      = lsp[0];
    const float inv2l2 = 0.5f / (l * l);

    const int icol = lane & 15;
    const int tb   = (lane >> 4) * 4;

    for (int tt = 0; tt < TILES; ++tt) {
        const int t0 = tbase + tt * TT;

        // ---- phase 0: exps -> LDS (Kx fp32, Ky fp32 + bf16 A-frag) ----
        // grid[g] = (ax[g>>7], ax[g&127])  =>  ax[j] = grid[j*2+1]
#pragma unroll
        for (int s = 0; s < 4; ++s) {
            const int k = s * THREADS + tid;   // 0..2047
            const int t = k >> 7;
            const int j = k & 127;
            int tg = t0 + t; if (tg >= n_target) tg = n_target - 1;
            const float ax = grid[j * 2 + 1];
            const float dx = xt[tg * 2 + 0] - ax;
            const float dy = xt[tg * 2 + 1] - ax;
            const float kxv = __expf(-dx * dx * inv2l2);
            const float kyv = __expf(-dy * dy * inv2l2);
            Kx[t * NA + j]   = kxv;
            Ky32[t * NA + j] = kyv;
            const int ss = j >> 5, g = (j & 31) >> 3, e = j & 7;
            kyA[((ss * 64) + g * 16 + (t & 15)) * 8 + e] = f2bf(kyv);
        }
        __syncthreads();

        // ---- Sx/Sy: shallow reduce, 32 groups (t x axis) x 16 lanes ----
        {
            const int grp  = tid >> 4;        // 0..31
            const int l16  = tid & 15;
            const int t    = grp >> 1;
            const int axis = grp & 1;
            const float* kb = axis ? Ky32 : Kx;
            const float4 q0 = *reinterpret_cast<const float4*>(&kb[t * NA + l16 * 8]);
            const float4 q1 = *reinterpret_cast<const float4*>(&kb[t * NA + l16 * 8 + 4]);
            float u = ((q0.x + q0.y) + (q0.z + q0.w)) + ((q1.x + q1.y) + (q1.z + q1.w));
            u += __shfl_xor(u, 1); u += __shfl_xor(u, 2);
            u += __shfl_xor(u, 4); u += __shfl_xor(u, 8);
            if (l16 == 0) { if (axis) psy[t] = u; else psx[t] = u; }
        }

        // ---- A-frags ----
        const short8* kap = reinterpret_cast<const short8*>(kyA);
        const short8 a0 = kap[0 * 64 + lane];
        const short8 a1 = kap[1 * 64 + lane];
        const short8 a2 = kap[2 * 64 + lane];
        const short8 a3 = kap[3 * 64 + lane];

        // ---- MFMA + stage-2 dot ----
        f32x4 p = {0.f, 0.f, 0.f, 0.f};
#define NTILE(NN, B0, B1, B2, B3)                                              \
        {                                                                      \
            f32x4 acc = {0.f, 0.f, 0.f, 0.f};                                  \
            acc = __builtin_amdgcn_mfma_f32_16x16x32_bf16(a0, B0, acc, 0, 0, 0); \
            acc = __builtin_amdgcn_mfma_f32_16x16x32_bf16(a1, B1, acc, 0, 0, 0); \
            acc = __builtin_amdgcn_mfma_f32_16x16x32_bf16(a2, B2, acc, 0, 0, 0); \
            acc = __builtin_amdgcn_mfma_f32_16x16x32_bf16(a3, B3, acc, 0, 0, 0); \
            const int i = (nh * 4 + (NN)) * 16 + icol;                         \
            p.x = fmaf(Kx[(tb + 0) * NA + i], acc.x, p.x);                     \
            p.y = fmaf(Kx[(tb + 1) * NA + i], acc.y, p.y);                     \
            p.z = fmaf(Kx[(tb + 2) * NA + i], acc.z, p.z);                     \
            p.w = fmaf(Kx[(tb + 3) * NA + i], acc.w, p.w);                     \
        }
        NTILE(0, b00, b01, b02, b03)
        NTILE(1, b10, b11, b12, b13)
        NTILE(2, b20, b21, b22, b23)
        NTILE(3, b30, b31, b32, b33)
#undef NTILE

        // ---- reduce numer over the 16 i-lanes (strides 1,2,4,8) ----
#pragma unroll
        for (int st = 1; st <= 8; st <<= 1) {
            p.x += __shfl_xor(p.x, st);
            p.y += __shfl_xor(p.y, st);
            p.z += __shfl_xor(p.z, st);
            p.w += __shfl_xor(p.w, st);
        }
        if (icol == 0) {
            red[c][nh][tb + 0] = p.x;
            red[c][nh][tb + 1] = p.y;
            red[c][nh][tb + 2] = p.z;
            red[c][nh][tb + 3] = p.w;
        }
        __syncthreads();

        // ---- epilogue: combine n-halves, normalize, write (64 outputs) ----
        // (reads red/psx/psy complete before the next tile's first barrier,
        //  and next-tile phase0 touches only Kx/Ky32/kyA -> no extra sync)
        if (tid < 4 * TT) {
            const int t  = tid & (TT - 1);
            const int cc = tid >> 4;            // requires TT == 16
            const int tg = t0 + t;
            if (tg < n_target) {
                const float numer = red[cc][0][t] + red[cc][1][t];
                const float val = numer / (psx[t] * psy[t]);
                if (cc < 2) out[tg * 2 + cc] = val;                      // means
                else        out[n_target * 2 + tg * 2 + (cc - 2)] = val; // sigmas
            }
        }
    }
}

extern "C" void kernel_launch(void* const* d_in, const int* in_sizes, int n_in,
                              void* d_out, int out_size, void* d_ws, size_t ws_size,
                              hipStream_t stream) {
    const float* fm   = (const float*)d_in[0];
    const float* grid = (const float*)d_in[1];
    const float* xt   = (const float*)d_in[2];
    const float* lsp  = (const float*)d_in[3];
    float* out = (float*)d_out;
    short* bfB = (short*)d_ws;                     // 4*8*4*64*8 bf16 = 128 KB

    const int n_target = in_sizes[2] / 2;          // 8192

    hipLaunchKernelGGL(pack_pre, dim3(128), dim3(128), 0, stream, fm, bfB);

    const int blocks = (n_target + TT * TILES - 1) / (TT * TILES);   // 256
    hipLaunchKernelGGL(cnp_mfma, dim3(blocks), dim3(THREADS), 0, stream,
                       bfB, grid, xt, lsp, out, n_target);
}